// Round 8
// baseline (248.833 us; speedup 1.0000x reference)
//
#include <hip/hip_runtime.h>
#include <hip/hip_fp16.h>

// ---------------------------------------------------------------------------
// GCN link prediction. Fixed-capacity bucket scatter (3-kernel, atomic-free
// allocation) -> per-bucket padded CSR -> per-node 8-lane-group gather.
// R12: k_csr 1024 threads, uint4 edge walks, 8 LDS hist replicas.
// R13: 8-edge unrolled agg loops, x8 padding. (best: 237.4)
// R14/R15/R16 (REVERTED): L2-residency attacks all regressed/neutral.
// R17 (REVERTED): wide gathers halved transactions but also halved
// occupancy (VGPR 32->~96) -> product unchanged, neutral.
// R18: degree-sorted node permutation. k_csr counting-sorts each bucket's
// 512 nodes by padded trip count (64 LDS bins) -> perm; agg kernels process
// w = perm[g] so the 8 groups in a wave have equal loop lengths, removing
// the ~20% exec-masked waste (E[max of 8 Poisson]/mean). Arithmetic per
// node unchanged -> bitwise-identical output.
// ---------------------------------------------------------------------------

#define NPB 512        // nodes per bucket (pack needs n < 2^23)
#define NBMAX 256      // supports n <= 131072
#define CHUNK 4096     // edges per scatter block
#define CAP 18432      // eb capacity per bucket (avg 16327, +16 sigma)
#define PCAP (CAP + 7 * NPB)  // col capacity per bucket (x8 node padding)

// Per-chunk bucket histogram -> cnt[c*NB+b] (coalesced row write).
__global__ __launch_bounds__(256) void k_hist(const int* __restrict__ dst,
                                              int* __restrict__ cnt, int E, int NB) {
    __shared__ int lh[NBMAX];
    int t = threadIdx.x, c = blockIdx.x;
    int e0 = c * CHUNK, e1 = min(e0 + CHUNK, E);
    for (int i = t; i < NB; i += 256) lh[i] = 0;
    __syncthreads();
    for (int e = e0 + t; e < e1; e += 256) atomicAdd(&lh[dst[e] >> 9], 1);
    __syncthreads();
    for (int i = t; i < NB; i += 256) cnt[c * NB + i] = lh[i];
}

// Per-bucket scan over chunks: rbase[c*NB+b] = b*CAP + prefix; bcnt[b] = total.
__global__ __launch_bounds__(256) void k_bscan(const int* __restrict__ cnt,
                                               int* __restrict__ rbase,
                                               int* __restrict__ bcnt,
                                               int NC, int NB) {
    __shared__ int sh[256];
    int t = threadIdx.x, b = blockIdx.x;
    int v[4];
    int part = 0;
#pragma unroll
    for (int j = 0; j < 4; ++j) {
        int c = t * 4 + j;
        v[j] = (c < NC) ? cnt[c * NB + b] : 0;
        part += v[j];
    }
    sh[t] = part;
    __syncthreads();
    for (int off = 1; off < 256; off <<= 1) {
        int a = (t >= off) ? sh[t - off] : 0;
        __syncthreads();
        sh[t] += a;
        __syncthreads();
    }
    int run = b * CAP + sh[t] - part;
#pragma unroll
    for (int j = 0; j < 4; ++j) {
        int c = t * 4 + j;
        if (c < NC) rbase[c * NB + b] = run;
        run += v[j];
    }
    if (t == 255) bcnt[b] = sh[255];
}

// Scatter with LDS staging: rank into LDS (bucket-ordered), then write out
// bucket-by-bucket with lanes striding -> contiguous-run global stores.
__global__ __launch_bounds__(256) void k_scatter(const int* __restrict__ src,
                                                 const int* __restrict__ dst,
                                                 const int* __restrict__ cnt,
                                                 const int* __restrict__ rbase,
                                                 unsigned* __restrict__ eb,
                                                 int E, int NB) {
    __shared__ unsigned buf[CHUNK];   // 16 KB
    __shared__ int lcnt[NBMAX];
    __shared__ int lbase[NBMAX];
    __shared__ int gbase[NBMAX];
    __shared__ int lrank[NBMAX];
    __shared__ int sh[256];
    int t = threadIdx.x, c = blockIdx.x;
    int e0 = c * CHUNK, e1 = min(e0 + CHUNK, E);
    int myc = (t < NB) ? cnt[c * NB + t] : 0;
    if (t < NB) {
        lcnt[t] = myc;
        gbase[t] = rbase[c * NB + t];
        lrank[t] = 0;
    }
    sh[t] = myc;
    __syncthreads();
    for (int off = 1; off < 256; off <<= 1) {  // scan for local bases
        int a = (t >= off) ? sh[t - off] : 0;
        __syncthreads();
        sh[t] += a;
        __syncthreads();
    }
    if (t < NB) lbase[t] = sh[t] - myc;
    __syncthreads();
    for (int e = e0 + t; e < e1; e += 256) {
        int s = src[e], d = dst[e];
        int b = d >> 9;
        int r = atomicAdd(&lrank[b], 1);
        buf[lbase[b] + r] = ((unsigned)s << 9) | (unsigned)(d & 511);
    }
    __syncthreads();
    int wv = t >> 6, lane = t & 63;
    for (int b = wv; b < NB; b += 4) {
        int base = lbase[b], gb = gbase[b], len = lcnt[b];
        for (int i = lane; i < len; i += 64) eb[gb + i] = buf[base + i];
    }
}

// Per-bucket padded CSR for 512-node buckets (fixed bases). 1024 threads,
// uint4-vectorized hist+scatter (identical thread->edge map keeps replica
// counts consistent), 8 hist replicas, 1-node-per-thread scan. x8 padding.
// Epilogue additionally counting-sorts the bucket's nodes by trip count
// (pc>>3) into perm for divergence-free agg waves.
__global__ __launch_bounds__(1024) void k_csr(const int* __restrict__ bcnt,
                                              const unsigned* __restrict__ eb,
                                              int* __restrict__ col,
                                              int* __restrict__ rpbeg,
                                              int* __restrict__ rpcnt,
                                              float* __restrict__ inv,
                                              int* __restrict__ perm,
                                              int n, int NB) {
    __shared__ int cnt[8][NPB];  // 16 KB
    __shared__ int cur[8][NPB];  // 16 KB
    __shared__ int sh[NPB];      // 2 KB
    __shared__ int dbin[64];
    __shared__ int dbase[64];
    int t = threadIdx.x, b = blockIdx.x;
    int r = (t >> 6) & 7;  // replica (2 waves share one)
    int nbase = b * NPB;
    int beg = b * CAP, end = beg + bcnt[b];
    int pb = b * PCAP;
    for (int i = t; i < 8 * NPB; i += 1024) ((int*)cnt)[i] = 0;
    if (t < 64) dbin[t] = 0;
    __syncthreads();
    int nedge = end - beg;
    int nv = nedge >> 2;                          // uint4 chunks
    const uint4* ebv = (const uint4*)(eb + beg);  // beg = b*CAP, 16B-aligned
    for (int i = t; i < nv; i += 1024) {
        uint4 p = ebv[i];
        atomicAdd(&cnt[r][p.x & 511u], 1);
        atomicAdd(&cnt[r][p.y & 511u], 1);
        atomicAdd(&cnt[r][p.z & 511u], 1);
        atomicAdd(&cnt[r][p.w & 511u], 1);
    }
    for (int i = beg + (nv << 2) + t; i < end; i += 1024)
        atomicAdd(&cnt[r][eb[i] & 511u], 1);
    __syncthreads();
    int c = 0, pc = 0;
    if (t < NPB) {  // one node per thread
        c = cnt[0][t] + cnt[1][t] + cnt[2][t] + cnt[3][t]
          + cnt[4][t] + cnt[5][t] + cnt[6][t] + cnt[7][t];
        pc = (c + 7) & ~7;
        sh[t] = pc;
    }
    __syncthreads();
    for (int off = 1; off < NPB; off <<= 1) {  // inclusive scan over 512
        int v = (t < NPB && t >= off) ? sh[t - off] : 0;
        __syncthreads();
        if (t < NPB) sh[t] += v;
        __syncthreads();
    }
    int mykey = 0, myrank = -1;
    if (t < NPB) {
        int base = pb + sh[t] - pc;
        int run = base;
#pragma unroll
        for (int rr = 0; rr < 8; ++rr) { cur[rr][t] = run; run += cnt[rr][t]; }
        int node = nbase + t;
        if (node < n) {
            rpbeg[node] = base;
            rpcnt[node] = pc;
            inv[node] = rsqrtf((float)(c + 1));
            for (int j = c; j < pc; ++j) col[base + j] = n;  // dummy zero row
            mykey = min(pc >> 3, 63);
            myrank = atomicAdd(&dbin[mykey], 1);  // degree-class rank
        }
    }
    __syncthreads();
    if (t == 0) {  // exclusive scan of the 64 degree bins
        int run = 0;
#pragma unroll 1
        for (int k = 0; k < 64; ++k) { dbase[k] = run; run += dbin[k]; }
    }
    __syncthreads();
    if (myrank >= 0) perm[nbase + dbase[mykey] + myrank] = nbase + t;
    for (int i = t; i < nv; i += 1024) {  // same map as hist -> same replica
        uint4 p = ebv[i];
        int p0 = atomicAdd(&cur[r][p.x & 511u], 1); col[p0] = (int)(p.x >> 9);
        int p1 = atomicAdd(&cur[r][p.y & 511u], 1); col[p1] = (int)(p.y >> 9);
        int p2 = atomicAdd(&cur[r][p.z & 511u], 1); col[p2] = (int)(p.z >> 9);
        int p3 = atomicAdd(&cur[r][p.w & 511u], 1); col[p3] = (int)(p.w >> 9);
    }
    for (int i = beg + (nv << 2) + t; i < end; i += 1024) {
        unsigned p = eb[i];
        int pos = atomicAdd(&cur[r][p & 511u], 1);
        col[pos] = (int)(p >> 9);
    }
}

// xw: 128 nodes/block, 4x4 register tile, x staged transposed in LDS.
// X[n+1][32] fp16 (uint2 = 4-half chunks); block 0 zeroes dummy rows X[n], hws[n].
__global__ __launch_bounds__(256) void k_xw(const float* __restrict__ x,
                                            const float* __restrict__ W1,
                                            const float* __restrict__ inv,
                                            uint2* __restrict__ X,
                                            unsigned* __restrict__ hws0, int n) {
    __shared__ float xsh[128 * 128];  // [k][node], 64 KB
    __shared__ float W1s[128 * 32];   // [k][col], 16 KB
    int t = threadIdx.x;
    int base = blockIdx.x * 128;
#pragma unroll
    for (int i = 0; i < 16; ++i) W1s[i * 256 + t] = W1[i * 256 + t];
    {
        int nl = t >> 1, kh = (t & 1) * 64;
        int node = base + nl;
        if (node < n) {
            const float4* xr = (const float4*)(x + (size_t)node * 128 + kh);
#pragma unroll
            for (int kk = 0; kk < 16; ++kk) {
                float4 v = xr[kk];
                int k = kh + kk * 4;
                xsh[(k + 0) * 128 + nl] = v.x;
                xsh[(k + 1) * 128 + nl] = v.y;
                xsh[(k + 2) * 128 + nl] = v.z;
                xsh[(k + 3) * 128 + nl] = v.w;
            }
        } else {
#pragma unroll
            for (int kk = 0; kk < 64; ++kk) xsh[(kh + kk) * 128 + nl] = 0.0f;
        }
    }
    if (blockIdx.x == 0) {  // dummy rows for padded-CSR gap entries
        if (t < 8) X[(size_t)n * 8 + t] = make_uint2(0u, 0u);
        else if (t < 16) hws0[(size_t)n * 8 + (t - 8)] = 0u;
    }
    __syncthreads();
    int tc = t & 7, tr = t >> 3;  // nodes 4*tr.., cols 4*tc..
    float acc[4][4] = {};
#pragma unroll 8
    for (int k = 0; k < 128; ++k) {
        float4 xv = *(const float4*)&xsh[k * 128 + 4 * tr];
        float4 wv = *(const float4*)&W1s[k * 32 + 4 * tc];
        acc[0][0] += xv.x * wv.x; acc[0][1] += xv.x * wv.y; acc[0][2] += xv.x * wv.z; acc[0][3] += xv.x * wv.w;
        acc[1][0] += xv.y * wv.x; acc[1][1] += xv.y * wv.y; acc[1][2] += xv.y * wv.z; acc[1][3] += xv.y * wv.w;
        acc[2][0] += xv.z * wv.x; acc[2][1] += xv.z * wv.y; acc[2][2] += xv.z * wv.z; acc[2][3] += xv.z * wv.w;
        acc[3][0] += xv.w * wv.x; acc[3][1] += xv.w * wv.y; acc[3][2] += xv.w * wv.z; acc[3][3] += xv.w * wv.w;
    }
#pragma unroll
    for (int i = 0; i < 4; ++i) {
        int node = base + 4 * tr + i;
        if (node < n) {
            float iw = inv[node];
            __half2 p0 = __floats2half2_rn(acc[i][0] * iw, acc[i][1] * iw);
            __half2 p1 = __floats2half2_rn(acc[i][2] * iw, acc[i][3] * iw);
            uint2 u;
            u.x = *(unsigned*)&p0;
            u.y = *(unsigned*)&p1;
            X[(size_t)node * 8 + tc] = u;
        }
    }
}

// acc[j] += f32(h[j]) — shaped for v_fma_mix_f32 (x*1.0+acc, exact).
__device__ __forceinline__ void add4h(float* a, uint2 v) {
    union { uint2 u; __half h[4]; } cv;
    cv.u = v;
#pragma unroll
    for (int j = 0; j < 4; ++j) a[j] = fmaf(__half2float(cv.h[j]), 1.0f, a[j]);
}

__device__ __forceinline__ void add2h(float* a, unsigned v) {
    union { unsigned u; __half h[2]; } cv;
    cv.u = v;
    a[0] = fmaf(__half2float(cv.h[0]), 1.0f, a[0]);
    a[1] = fmaf(__half2float(cv.h[1]), 1.0f, a[1]);
}

// Layer 1: one node per 8-lane group via degree-sorted perm; lane owns 4 cols
// (uint2 of the 64 B row). Private f32 accumulation. Branch-free x8 edge loop
// (2x int4 col + 8 gathers in flight). Epilogue: relu+bias in-lane, W2 GEMM
// via group shfl.
__global__ __launch_bounds__(256) void k_agg1(const int* __restrict__ perm,
                                              const int* __restrict__ rpbeg,
                                              const int* __restrict__ rpcnt,
                                              const int* __restrict__ col,
                                              const uint2* __restrict__ X2,
                                              const float* __restrict__ inv,
                                              const float* __restrict__ b1,
                                              const float* __restrict__ W2,
                                              __half2* __restrict__ hws, int n) {
    __shared__ float W2s[512];
    int t = threadIdx.x;
    W2s[t] = W2[t];
    W2s[256 + t] = W2[256 + t];
    __syncthreads();
    int g = (blockIdx.x * 256 + t) >> 3;
    if (g >= n) return;  // group-uniform (8 lanes share g)
    int w = perm[g];     // degree-sorted node id
    int q = t & 7;
    int grpbase = (t & 63) & 56;
    float bb[4];
#pragma unroll
    for (int j = 0; j < 4; ++j) bb[j] = b1[4 * q + j];
    int beg = rpbeg[w], endp = beg + rpcnt[w];
    float a[4] = {};
    add4h(a, X2[(size_t)w * 8 + q]);  // self-loop
    for (int i = beg; i < endp; i += 8) {
        int4 c4 = *(const int4*)(col + i);      // 16B-aligned by construction
        int4 c8 = *(const int4*)(col + i + 4);
        uint2 v0 = X2[(size_t)c4.x * 8 + q];
        uint2 v1 = X2[(size_t)c4.y * 8 + q];
        uint2 v2 = X2[(size_t)c4.z * 8 + q];
        uint2 v3 = X2[(size_t)c4.w * 8 + q];
        uint2 v4 = X2[(size_t)c8.x * 8 + q];
        uint2 v5 = X2[(size_t)c8.y * 8 + q];
        uint2 v6 = X2[(size_t)c8.z * 8 + q];
        uint2 v7 = X2[(size_t)c8.w * 8 + q];
        add4h(a, v0);
        add4h(a, v1);
        add4h(a, v2);
        add4h(a, v3);
        add4h(a, v4);
        add4h(a, v5);
        add4h(a, v6);
        add4h(a, v7);
    }
    float iw = inv[w];
    float h[4];
#pragma unroll
    for (int j = 0; j < 4; ++j) h[j] = fmaxf(iw * a[j] + bb[j], 0.0f);
    // hws[w][2q],[2q+1] = iw * sum_k h[k] * W2[k][c]
    float s0 = 0.0f, s1 = 0.0f;
#pragma unroll
    for (int qq = 0; qq < 8; ++qq) {
#pragma unroll
        for (int j = 0; j < 4; ++j) {
            float hv = __shfl(h[j], grpbase + qq);
            float2 wv = *(const float2*)&W2s[(4 * qq + j) * 16 + 2 * q];
            s0 = fmaf(hv, wv.x, s0);
            s1 = fmaf(hv, wv.y, s1);
        }
    }
    hws[(size_t)w * 8 + q] = __floats2half2_rn(s0 * iw, s1 * iw);
}

// Layer 2: one node per 8-lane group via perm; lane owns 2 cols (half2 of
// the 32 B row). Branch-free x8 edge loop.
__global__ __launch_bounds__(256) void k_agg2(const int* __restrict__ perm,
                                              const int* __restrict__ rpbeg,
                                              const int* __restrict__ rpcnt,
                                              const int* __restrict__ col,
                                              const unsigned* __restrict__ H,
                                              const float* __restrict__ inv,
                                              const float* __restrict__ b2,
                                              unsigned* __restrict__ z, int n) {
    int t = threadIdx.x;
    int g = (blockIdx.x * 256 + t) >> 3;
    if (g >= n) return;
    int w = perm[g];
    int q = t & 7;
    float bb0 = b2[2 * q], bb1 = b2[2 * q + 1];
    int beg = rpbeg[w], endp = beg + rpcnt[w];
    float a[2] = {};
    add2h(a, H[(size_t)w * 8 + q]);  // self-loop
    for (int i = beg; i < endp; i += 8) {
        int4 c4 = *(const int4*)(col + i);
        int4 c8 = *(const int4*)(col + i + 4);
        unsigned v0 = H[(size_t)c4.x * 8 + q];
        unsigned v1 = H[(size_t)c4.y * 8 + q];
        unsigned v2 = H[(size_t)c4.z * 8 + q];
        unsigned v3 = H[(size_t)c4.w * 8 + q];
        unsigned v4 = H[(size_t)c8.x * 8 + q];
        unsigned v5 = H[(size_t)c8.y * 8 + q];
        unsigned v6 = H[(size_t)c8.z * 8 + q];
        unsigned v7 = H[(size_t)c8.w * 8 + q];
        add2h(a, v0);
        add2h(a, v1);
        add2h(a, v2);
        add2h(a, v3);
        add2h(a, v4);
        add2h(a, v5);
        add2h(a, v6);
        add2h(a, v7);
    }
    float iw = inv[w];
    __half2 r = __floats2half2_rn(iw * a[0] + bb0, iw * a[1] + bb1);
    z[(size_t)w * 8 + q] = *(unsigned*)&r;
}

__device__ __forceinline__ float dot8h(uint4 u, uint4 v, float s) {
    const __half2* pu = (const __half2*)&u;
    const __half2* pv = (const __half2*)&v;
#pragma unroll
    for (int i = 0; i < 4; ++i) {
#if __has_builtin(__builtin_amdgcn_fdot2)
        s = __builtin_amdgcn_fdot2(pu[i], pv[i], s, false);
#else
        float2 a = __half22float2(pu[i]);
        float2 b = __half22float2(pv[i]);
        s += a.x * b.x + a.y * b.y;
#endif
    }
    return s;
}

__global__ void k_decode(const int* __restrict__ eli, const uint4* __restrict__ z4,
                         float* __restrict__ out, int L) {
    int e = blockIdx.x * blockDim.x + threadIdx.x;
    if (e >= L) return;
    int a = eli[e], b = eli[L + e];
    uint4 ua0 = z4[(size_t)a * 2], ua1 = z4[(size_t)a * 2 + 1];
    uint4 ub0 = z4[(size_t)b * 2], ub1 = z4[(size_t)b * 2 + 1];
    out[e] = dot8h(ua1, ub1, dot8h(ua0, ub0, 0.0f));
}

extern "C" void kernel_launch(void* const* d_in, const int* in_sizes, int n_in,
                              void* d_out, int out_size, void* d_ws, size_t ws_size,
                              hipStream_t stream) {
    const float* x   = (const float*)d_in[0];
    const int*   ei  = (const int*)d_in[1];
    const int*   eli = (const int*)d_in[2];
    const float* W1  = (const float*)d_in[3];
    const float* b1  = (const float*)d_in[4];
    const float* W2  = (const float*)d_in[5];
    const float* b2  = (const float*)d_in[6];
    float* out = (float*)d_out;

    int n = in_sizes[0] / 128;
    int E = in_sizes[1] / 2;
    int L = in_sizes[2] / 2;
    const int* src = ei;
    const int* dst = ei + E;
    int NB = (n + NPB - 1) / NPB;      // 196 for n=100k
    int NC = (E + CHUNK - 1) / CHUNK;  // 782 for E=3.2M

    // ws: X (n+1)x8 uint2 | hws (n+1)x8 half2 | z n x 8 half2 | inv n f |
    //     rpbeg n | rpcnt n | perm n | eb NB*CAP | col NB*PCAP | cnt NC*NB |
    //     rbase NC*NB | bcnt NB
    uint2* X       = (uint2*)d_ws;
    unsigned* hws  = (unsigned*)(X + (size_t)(n + 1) * 8);
    unsigned* z    = hws + (size_t)(n + 1) * 8;
    float* inv     = (float*)(z + (size_t)n * 8);
    int* rpbeg     = (int*)(inv + n);
    int* rpcnt     = rpbeg + n;
    int* perm      = rpcnt + n;
    unsigned* eb   = (unsigned*)(perm + n);
    int* col       = (int*)(eb + (size_t)NB * CAP);
    int* cnt       = col + (size_t)NB * PCAP;
    int* rbase     = cnt + (size_t)NC * NB;
    int* bcnt      = rbase + (size_t)NC * NB;

    k_hist<<<NC, 256, 0, stream>>>(dst, cnt, E, NB);
    k_bscan<<<NB, 256, 0, stream>>>(cnt, rbase, bcnt, NC, NB);
    k_scatter<<<NC, 256, 0, stream>>>(src, dst, cnt, rbase, eb, E, NB);
    k_csr<<<NB, 1024, 0, stream>>>(bcnt, eb, col, rpbeg, rpcnt, inv, perm, n, NB);
    k_xw<<<(n + 127) / 128, 256, 0, stream>>>(x, W1, inv, X, hws, n);
    k_agg1<<<((size_t)n * 8 + 255) / 256, 256, 0, stream>>>(perm, rpbeg, rpcnt, col, X, inv, b1, W2, (__half2*)hws, n);
    k_agg2<<<((size_t)n * 8 + 255) / 256, 256, 0, stream>>>(perm, rpbeg, rpcnt, col, hws, inv, b2, z, n);
    k_decode<<<(L + 255) / 256, 256, 0, stream>>>(eli, (const uint4*)z, out, L);
}

// Round 9
// 236.316 us; speedup vs baseline: 1.0530x; 1.0530x over previous
//
#include <hip/hip_runtime.h>
#include <hip/hip_fp16.h>

// ---------------------------------------------------------------------------
// GCN link prediction. Fixed-capacity bucket scatter (3-kernel, atomic-free
// allocation) -> per-bucket padded CSR -> per-node 8-lane-group gather with
// zero cross-lane reduction.  == R13 configuration (best: 237.4 us) ==
// R12: k_csr widened to 1024 threads (16 waves/CU), uint4 edge walks,
//      8 LDS hist replicas.
// R13: node segments padded to x8; agg edge loops fully unrolled to 8
//      edges/iter (2x int4 col + 8 gathers in flight).
// R14-R18 (ALL REVERTED, counters invariant): feature-split (2x row
// accesses), NT hints (no FETCH change), node-split (overheads), wide
// gathers (VGPR halved occupancy), degree-sort perm (scattered stores).
// k_agg1 pinned at ~43 us / 113 MB L2-fill / ~2.7 TB/s across all six
// levers -> random-line L3->L2 fill bandwidth floor. Terminal config.
// ---------------------------------------------------------------------------

#define NPB 512        // nodes per bucket (pack needs n < 2^23)
#define NBMAX 256      // supports n <= 131072
#define CHUNK 4096     // edges per scatter block
#define CAP 18432      // eb capacity per bucket (avg 16327, +16 sigma)
#define PCAP (CAP + 7 * NPB)  // col capacity per bucket (x8 node padding)

// Per-chunk bucket histogram -> cnt[c*NB+b] (coalesced row write).
__global__ __launch_bounds__(256) void k_hist(const int* __restrict__ dst,
                                              int* __restrict__ cnt, int E, int NB) {
    __shared__ int lh[NBMAX];
    int t = threadIdx.x, c = blockIdx.x;
    int e0 = c * CHUNK, e1 = min(e0 + CHUNK, E);
    for (int i = t; i < NB; i += 256) lh[i] = 0;
    __syncthreads();
    for (int e = e0 + t; e < e1; e += 256) atomicAdd(&lh[dst[e] >> 9], 1);
    __syncthreads();
    for (int i = t; i < NB; i += 256) cnt[c * NB + i] = lh[i];
}

// Per-bucket scan over chunks: rbase[c*NB+b] = b*CAP + prefix; bcnt[b] = total.
__global__ __launch_bounds__(256) void k_bscan(const int* __restrict__ cnt,
                                               int* __restrict__ rbase,
                                               int* __restrict__ bcnt,
                                               int NC, int NB) {
    __shared__ int sh[256];
    int t = threadIdx.x, b = blockIdx.x;
    int v[4];
    int part = 0;
#pragma unroll
    for (int j = 0; j < 4; ++j) {
        int c = t * 4 + j;
        v[j] = (c < NC) ? cnt[c * NB + b] : 0;
        part += v[j];
    }
    sh[t] = part;
    __syncthreads();
    for (int off = 1; off < 256; off <<= 1) {
        int a = (t >= off) ? sh[t - off] : 0;
        __syncthreads();
        sh[t] += a;
        __syncthreads();
    }
    int run = b * CAP + sh[t] - part;
#pragma unroll
    for (int j = 0; j < 4; ++j) {
        int c = t * 4 + j;
        if (c < NC) rbase[c * NB + b] = run;
        run += v[j];
    }
    if (t == 255) bcnt[b] = sh[255];
}

// Scatter with LDS staging: rank into LDS (bucket-ordered), then write out
// bucket-by-bucket with lanes striding -> contiguous-run global stores.
__global__ __launch_bounds__(256) void k_scatter(const int* __restrict__ src,
                                                 const int* __restrict__ dst,
                                                 const int* __restrict__ cnt,
                                                 const int* __restrict__ rbase,
                                                 unsigned* __restrict__ eb,
                                                 int E, int NB) {
    __shared__ unsigned buf[CHUNK];   // 16 KB
    __shared__ int lcnt[NBMAX];
    __shared__ int lbase[NBMAX];
    __shared__ int gbase[NBMAX];
    __shared__ int lrank[NBMAX];
    __shared__ int sh[256];
    int t = threadIdx.x, c = blockIdx.x;
    int e0 = c * CHUNK, e1 = min(e0 + CHUNK, E);
    int myc = (t < NB) ? cnt[c * NB + t] : 0;
    if (t < NB) {
        lcnt[t] = myc;
        gbase[t] = rbase[c * NB + t];
        lrank[t] = 0;
    }
    sh[t] = myc;
    __syncthreads();
    for (int off = 1; off < 256; off <<= 1) {  // scan for local bases
        int a = (t >= off) ? sh[t - off] : 0;
        __syncthreads();
        sh[t] += a;
        __syncthreads();
    }
    if (t < NB) lbase[t] = sh[t] - myc;
    __syncthreads();
    for (int e = e0 + t; e < e1; e += 256) {
        int s = src[e], d = dst[e];
        int b = d >> 9;
        int r = atomicAdd(&lrank[b], 1);
        buf[lbase[b] + r] = ((unsigned)s << 9) | (unsigned)(d & 511);
    }
    __syncthreads();
    int wv = t >> 6, lane = t & 63;
    for (int b = wv; b < NB; b += 4) {
        int base = lbase[b], gb = gbase[b], len = lcnt[b];
        for (int i = lane; i < len; i += 64) eb[gb + i] = buf[base + i];
    }
}

// Per-bucket padded CSR for 512-node buckets (fixed bases). 1024 threads,
// uint4-vectorized hist+scatter (identical thread->edge map keeps replica
// counts consistent), 8 hist replicas, 1-node-per-thread scan. x8 padding.
__global__ __launch_bounds__(1024) void k_csr(const int* __restrict__ bcnt,
                                              const unsigned* __restrict__ eb,
                                              int* __restrict__ col,
                                              int* __restrict__ rpbeg,
                                              int* __restrict__ rpcnt,
                                              float* __restrict__ inv,
                                              int n, int NB) {
    __shared__ int cnt[8][NPB];  // 16 KB
    __shared__ int cur[8][NPB];  // 16 KB
    __shared__ int sh[NPB];      // 2 KB
    int t = threadIdx.x, b = blockIdx.x;
    int r = (t >> 6) & 7;  // replica (2 waves share one)
    int nbase = b * NPB;
    int beg = b * CAP, end = beg + bcnt[b];
    int pb = b * PCAP;
    for (int i = t; i < 8 * NPB; i += 1024) ((int*)cnt)[i] = 0;
    __syncthreads();
    int nedge = end - beg;
    int nv = nedge >> 2;                          // uint4 chunks
    const uint4* ebv = (const uint4*)(eb + beg);  // beg = b*CAP, 16B-aligned
    for (int i = t; i < nv; i += 1024) {
        uint4 p = ebv[i];
        atomicAdd(&cnt[r][p.x & 511u], 1);
        atomicAdd(&cnt[r][p.y & 511u], 1);
        atomicAdd(&cnt[r][p.z & 511u], 1);
        atomicAdd(&cnt[r][p.w & 511u], 1);
    }
    for (int i = beg + (nv << 2) + t; i < end; i += 1024)
        atomicAdd(&cnt[r][eb[i] & 511u], 1);
    __syncthreads();
    int c = 0, pc = 0;
    if (t < NPB) {  // one node per thread
        c = cnt[0][t] + cnt[1][t] + cnt[2][t] + cnt[3][t]
          + cnt[4][t] + cnt[5][t] + cnt[6][t] + cnt[7][t];
        pc = (c + 7) & ~7;
        sh[t] = pc;
    }
    __syncthreads();
    for (int off = 1; off < NPB; off <<= 1) {  // inclusive scan over 512
        int v = (t < NPB && t >= off) ? sh[t - off] : 0;
        __syncthreads();
        if (t < NPB) sh[t] += v;
        __syncthreads();
    }
    if (t < NPB) {
        int base = pb + sh[t] - pc;
        int run = base;
#pragma unroll
        for (int rr = 0; rr < 8; ++rr) { cur[rr][t] = run; run += cnt[rr][t]; }
        int node = nbase + t;
        if (node < n) {
            rpbeg[node] = base;
            rpcnt[node] = pc;
            inv[node] = rsqrtf((float)(c + 1));
            for (int j = c; j < pc; ++j) col[base + j] = n;  // dummy zero row
        }
    }
    __syncthreads();
    for (int i = t; i < nv; i += 1024) {  // same map as hist -> same replica
        uint4 p = ebv[i];
        int p0 = atomicAdd(&cur[r][p.x & 511u], 1); col[p0] = (int)(p.x >> 9);
        int p1 = atomicAdd(&cur[r][p.y & 511u], 1); col[p1] = (int)(p.y >> 9);
        int p2 = atomicAdd(&cur[r][p.z & 511u], 1); col[p2] = (int)(p.z >> 9);
        int p3 = atomicAdd(&cur[r][p.w & 511u], 1); col[p3] = (int)(p.w >> 9);
    }
    for (int i = beg + (nv << 2) + t; i < end; i += 1024) {
        unsigned p = eb[i];
        int pos = atomicAdd(&cur[r][p & 511u], 1);
        col[pos] = (int)(p >> 9);
    }
}

// xw: 128 nodes/block, 4x4 register tile, x staged transposed in LDS.
// X[n+1][32] fp16 (uint2 = 4-half chunks); block 0 zeroes dummy rows X[n], hws[n].
__global__ __launch_bounds__(256) void k_xw(const float* __restrict__ x,
                                            const float* __restrict__ W1,
                                            const float* __restrict__ inv,
                                            uint2* __restrict__ X,
                                            unsigned* __restrict__ hws0, int n) {
    __shared__ float xsh[128 * 128];  // [k][node], 64 KB
    __shared__ float W1s[128 * 32];   // [k][col], 16 KB
    int t = threadIdx.x;
    int base = blockIdx.x * 128;
#pragma unroll
    for (int i = 0; i < 16; ++i) W1s[i * 256 + t] = W1[i * 256 + t];
    {
        int nl = t >> 1, kh = (t & 1) * 64;
        int node = base + nl;
        if (node < n) {
            const float4* xr = (const float4*)(x + (size_t)node * 128 + kh);
#pragma unroll
            for (int kk = 0; kk < 16; ++kk) {
                float4 v = xr[kk];
                int k = kh + kk * 4;
                xsh[(k + 0) * 128 + nl] = v.x;
                xsh[(k + 1) * 128 + nl] = v.y;
                xsh[(k + 2) * 128 + nl] = v.z;
                xsh[(k + 3) * 128 + nl] = v.w;
            }
        } else {
#pragma unroll
            for (int kk = 0; kk < 64; ++kk) xsh[(kh + kk) * 128 + nl] = 0.0f;
        }
    }
    if (blockIdx.x == 0) {  // dummy rows for padded-CSR gap entries
        if (t < 8) X[(size_t)n * 8 + t] = make_uint2(0u, 0u);
        else if (t < 16) hws0[(size_t)n * 8 + (t - 8)] = 0u;
    }
    __syncthreads();
    int tc = t & 7, tr = t >> 3;  // nodes 4*tr.., cols 4*tc..
    float acc[4][4] = {};
#pragma unroll 8
    for (int k = 0; k < 128; ++k) {
        float4 xv = *(const float4*)&xsh[k * 128 + 4 * tr];
        float4 wv = *(const float4*)&W1s[k * 32 + 4 * tc];
        acc[0][0] += xv.x * wv.x; acc[0][1] += xv.x * wv.y; acc[0][2] += xv.x * wv.z; acc[0][3] += xv.x * wv.w;
        acc[1][0] += xv.y * wv.x; acc[1][1] += xv.y * wv.y; acc[1][2] += xv.y * wv.z; acc[1][3] += xv.y * wv.w;
        acc[2][0] += xv.z * wv.x; acc[2][1] += xv.z * wv.y; acc[2][2] += xv.z * wv.z; acc[2][3] += xv.z * wv.w;
        acc[3][0] += xv.w * wv.x; acc[3][1] += xv.w * wv.y; acc[3][2] += xv.w * wv.z; acc[3][3] += xv.w * wv.w;
    }
#pragma unroll
    for (int i = 0; i < 4; ++i) {
        int node = base + 4 * tr + i;
        if (node < n) {
            float iw = inv[node];
            __half2 p0 = __floats2half2_rn(acc[i][0] * iw, acc[i][1] * iw);
            __half2 p1 = __floats2half2_rn(acc[i][2] * iw, acc[i][3] * iw);
            uint2 u;
            u.x = *(unsigned*)&p0;
            u.y = *(unsigned*)&p1;
            X[(size_t)node * 8 + tc] = u;
        }
    }
}

// acc[j] += f32(h[j]) — shaped for v_fma_mix_f32 (x*1.0+acc, exact).
__device__ __forceinline__ void add4h(float* a, uint2 v) {
    union { uint2 u; __half h[4]; } cv;
    cv.u = v;
#pragma unroll
    for (int j = 0; j < 4; ++j) a[j] = fmaf(__half2float(cv.h[j]), 1.0f, a[j]);
}

__device__ __forceinline__ void add2h(float* a, unsigned v) {
    union { unsigned u; __half h[2]; } cv;
    cv.u = v;
    a[0] = fmaf(__half2float(cv.h[0]), 1.0f, a[0]);
    a[1] = fmaf(__half2float(cv.h[1]), 1.0f, a[1]);
}

// Layer 1: one node per 8-lane group; lane owns 4 cols (uint2 of the 64 B row).
// Private f32 accumulation (no cross-lane reduce). Branch-free x8 edge loop
// (2x int4 col + 8 gathers in flight). Epilogue: relu+bias in-lane, W2 GEMM
// via group shfl.
__global__ __launch_bounds__(256) void k_agg1(const int* __restrict__ rpbeg,
                                              const int* __restrict__ rpcnt,
                                              const int* __restrict__ col,
                                              const uint2* __restrict__ X2,
                                              const float* __restrict__ inv,
                                              const float* __restrict__ b1,
                                              const float* __restrict__ W2,
                                              __half2* __restrict__ hws, int n) {
    __shared__ float W2s[512];
    int t = threadIdx.x;
    W2s[t] = W2[t];
    W2s[256 + t] = W2[256 + t];
    __syncthreads();
    int w = (blockIdx.x * 256 + t) >> 3;
    if (w >= n) return;  // group-uniform (8 lanes share w)
    int q = t & 7;
    int grpbase = (t & 63) & 56;
    float bb[4];
#pragma unroll
    for (int j = 0; j < 4; ++j) bb[j] = b1[4 * q + j];
    int beg = rpbeg[w], endp = beg + rpcnt[w];
    float a[4] = {};
    add4h(a, X2[(size_t)w * 8 + q]);  // self-loop
    for (int i = beg; i < endp; i += 8) {
        int4 c4 = *(const int4*)(col + i);      // 16B-aligned by construction
        int4 c8 = *(const int4*)(col + i + 4);
        uint2 v0 = X2[(size_t)c4.x * 8 + q];
        uint2 v1 = X2[(size_t)c4.y * 8 + q];
        uint2 v2 = X2[(size_t)c4.z * 8 + q];
        uint2 v3 = X2[(size_t)c4.w * 8 + q];
        uint2 v4 = X2[(size_t)c8.x * 8 + q];
        uint2 v5 = X2[(size_t)c8.y * 8 + q];
        uint2 v6 = X2[(size_t)c8.z * 8 + q];
        uint2 v7 = X2[(size_t)c8.w * 8 + q];
        add4h(a, v0);
        add4h(a, v1);
        add4h(a, v2);
        add4h(a, v3);
        add4h(a, v4);
        add4h(a, v5);
        add4h(a, v6);
        add4h(a, v7);
    }
    float iw = inv[w];
    float h[4];
#pragma unroll
    for (int j = 0; j < 4; ++j) h[j] = fmaxf(iw * a[j] + bb[j], 0.0f);
    // hws[w][2q],[2q+1] = iw * sum_k h[k] * W2[k][c]
    float s0 = 0.0f, s1 = 0.0f;
#pragma unroll
    for (int qq = 0; qq < 8; ++qq) {
#pragma unroll
        for (int j = 0; j < 4; ++j) {
            float hv = __shfl(h[j], grpbase + qq);
            float2 wv = *(const float2*)&W2s[(4 * qq + j) * 16 + 2 * q];
            s0 = fmaf(hv, wv.x, s0);
            s1 = fmaf(hv, wv.y, s1);
        }
    }
    hws[(size_t)w * 8 + q] = __floats2half2_rn(s0 * iw, s1 * iw);
}

// Layer 2: one node per 8-lane group; lane owns 2 cols (half2 of the 32 B row).
// Branch-free x8 edge loop (2x int4 col + 8 gathers in flight).
__global__ __launch_bounds__(256) void k_agg2(const int* __restrict__ rpbeg,
                                              const int* __restrict__ rpcnt,
                                              const int* __restrict__ col,
                                              const unsigned* __restrict__ H,
                                              const float* __restrict__ inv,
                                              const float* __restrict__ b2,
                                              unsigned* __restrict__ z, int n) {
    int t = threadIdx.x;
    int w = (blockIdx.x * 256 + t) >> 3;
    if (w >= n) return;
    int q = t & 7;
    float bb0 = b2[2 * q], bb1 = b2[2 * q + 1];
    int beg = rpbeg[w], endp = beg + rpcnt[w];
    float a[2] = {};
    add2h(a, H[(size_t)w * 8 + q]);  // self-loop
    for (int i = beg; i < endp; i += 8) {
        int4 c4 = *(const int4*)(col + i);
        int4 c8 = *(const int4*)(col + i + 4);
        unsigned v0 = H[(size_t)c4.x * 8 + q];
        unsigned v1 = H[(size_t)c4.y * 8 + q];
        unsigned v2 = H[(size_t)c4.z * 8 + q];
        unsigned v3 = H[(size_t)c4.w * 8 + q];
        unsigned v4 = H[(size_t)c8.x * 8 + q];
        unsigned v5 = H[(size_t)c8.y * 8 + q];
        unsigned v6 = H[(size_t)c8.z * 8 + q];
        unsigned v7 = H[(size_t)c8.w * 8 + q];
        add2h(a, v0);
        add2h(a, v1);
        add2h(a, v2);
        add2h(a, v3);
        add2h(a, v4);
        add2h(a, v5);
        add2h(a, v6);
        add2h(a, v7);
    }
    float iw = inv[w];
    __half2 r = __floats2half2_rn(iw * a[0] + bb0, iw * a[1] + bb1);
    z[(size_t)w * 8 + q] = *(unsigned*)&r;
}

__device__ __forceinline__ float dot8h(uint4 u, uint4 v, float s) {
    const __half2* pu = (const __half2*)&u;
    const __half2* pv = (const __half2*)&v;
#pragma unroll
    for (int i = 0; i < 4; ++i) {
#if __has_builtin(__builtin_amdgcn_fdot2)
        s = __builtin_amdgcn_fdot2(pu[i], pv[i], s, false);
#else
        float2 a = __half22float2(pu[i]);
        float2 b = __half22float2(pv[i]);
        s += a.x * b.x + a.y * b.y;
#endif
    }
    return s;
}

__global__ void k_decode(const int* __restrict__ eli, const uint4* __restrict__ z4,
                         float* __restrict__ out, int L) {
    int e = blockIdx.x * blockDim.x + threadIdx.x;
    if (e >= L) return;
    int a = eli[e], b = eli[L + e];
    uint4 ua0 = z4[(size_t)a * 2], ua1 = z4[(size_t)a * 2 + 1];
    uint4 ub0 = z4[(size_t)b * 2], ub1 = z4[(size_t)b * 2 + 1];
    out[e] = dot8h(ua1, ub1, dot8h(ua0, ub0, 0.0f));
}

extern "C" void kernel_launch(void* const* d_in, const int* in_sizes, int n_in,
                              void* d_out, int out_size, void* d_ws, size_t ws_size,
                              hipStream_t stream) {
    const float* x   = (const float*)d_in[0];
    const int*   ei  = (const int*)d_in[1];
    const int*   eli = (const int*)d_in[2];
    const float* W1  = (const float*)d_in[3];
    const float* b1  = (const float*)d_in[4];
    const float* W2  = (const float*)d_in[5];
    const float* b2  = (const float*)d_in[6];
    float* out = (float*)d_out;

    int n = in_sizes[0] / 128;
    int E = in_sizes[1] / 2;
    int L = in_sizes[2] / 2;
    const int* src = ei;
    const int* dst = ei + E;
    int NB = (n + NPB - 1) / NPB;      // 196 for n=100k
    int NC = (E + CHUNK - 1) / CHUNK;  // 782 for E=3.2M

    // ws: X (n+1)x8 uint2 | hws (n+1)x8 half2 | z n x 8 half2 | inv n f |
    //     rpbeg n | rpcnt n | eb NB*CAP | col NB*PCAP | cnt NC*NB |
    //     rbase NC*NB | bcnt NB
    uint2* X       = (uint2*)d_ws;
    unsigned* hws  = (unsigned*)(X + (size_t)(n + 1) * 8);
    unsigned* z    = hws + (size_t)(n + 1) * 8;
    float* inv     = (float*)(z + (size_t)n * 8);
    int* rpbeg     = (int*)(inv + n);
    int* rpcnt     = rpbeg + n;
    unsigned* eb   = (unsigned*)(rpcnt + n);
    int* col       = (int*)(eb + (size_t)NB * CAP);
    int* cnt       = col + (size_t)NB * PCAP;
    int* rbase     = cnt + (size_t)NC * NB;
    int* bcnt      = rbase + (size_t)NC * NB;

    k_hist<<<NC, 256, 0, stream>>>(dst, cnt, E, NB);
    k_bscan<<<NB, 256, 0, stream>>>(cnt, rbase, bcnt, NC, NB);
    k_scatter<<<NC, 256, 0, stream>>>(src, dst, cnt, rbase, eb, E, NB);
    k_csr<<<NB, 1024, 0, stream>>>(bcnt, eb, col, rpbeg, rpcnt, inv, n, NB);
    k_xw<<<(n + 127) / 128, 256, 0, stream>>>(x, W1, inv, X, hws, n);
    k_agg1<<<((size_t)n * 8 + 255) / 256, 256, 0, stream>>>(rpbeg, rpcnt, col, X, inv, b1, W2, (__half2*)hws, n);
    k_agg2<<<((size_t)n * 8 + 255) / 256, 256, 0, stream>>>(rpbeg, rpcnt, col, hws, inv, b2, z, n);
    k_decode<<<(L + 255) / 256, 256, 0, stream>>>(eli, (const uint4*)z, out, L);
}